// Round 7
// baseline (713.696 us; speedup 1.0000x reference)
//
#include <hip/hip_runtime.h>

// ---------- types ----------
typedef __attribute__((ext_vector_type(8))) short bf16x8;
typedef __attribute__((ext_vector_type(8))) unsigned short u16x8;
typedef __attribute__((ext_vector_type(4))) unsigned short u16x4;
typedef __attribute__((ext_vector_type(4))) float f32x4;
typedef __attribute__((ext_vector_type(2))) float f32x2;

__device__ __forceinline__ unsigned short f2bf(float f) {
  union { float f; unsigned u; } v; v.f = f;
  unsigned r = v.u + 0x7FFFu + ((v.u >> 16) & 1u);
  return (unsigned short)(r >> 16);
}
__device__ __forceinline__ float bf2f(unsigned short s) {
  union { unsigned u; float f; } v; v.u = ((unsigned)s) << 16;
  return v.f;
}

// DPP-based wave64 sum; result valid in lane 63 only.
template <int CTRL>
__device__ __forceinline__ float dpp_add(float v) {
  int m = __builtin_amdgcn_update_dpp(0, __float_as_int(v), CTRL, 0xf, 0xf, true);
  return v + __int_as_float(m);
}
__device__ __forceinline__ float wave_sum63(float v) {
  v = dpp_add<0x111>(v);  // row_shr:1
  v = dpp_add<0x112>(v);  // row_shr:2
  v = dpp_add<0x114>(v);  // row_shr:4
  v = dpp_add<0x118>(v);  // row_shr:8  -> lane15 of each row has row sum
  v = dpp_add<0x142>(v);  // row_bcast:15
  v = dpp_add<0x143>(v);  // row_bcast:31 -> lane63 has wave sum
  return v;
}

// Problem constants
// B=64 T=512 E=300 V=50000 H=2048 WP=2 OUT=5
// padded: EP=320, TP=516, KP=1600, M=B*T=32768

// ---------- kernel 1: W1 -> W1bT bf16 [2048][1600] (transposed, K-padded) ----------
__global__ __launch_bounds__(256) void prepw1_kernel(
    const float* __restrict__ W1, unsigned short* __restrict__ W1bT) {
  __shared__ float tile[64][65];
  int kb = blockIdx.x % 25;   // K tile (padded K = 1600 = 25*64)
  int hb = blockIdx.x / 25;   // H tile (2048 = 32*64)
  int win = kb / 5;
  int e0 = (kb % 5) << 6;
  int hh = threadIdx.x & 63;
  int kq = threadIdx.x >> 6;
#pragma unroll
  for (int kk = kq; kk < 64; kk += 4) {
    int e = e0 + kk;
    float v = 0.f;
    if (e < 300) v = W1[(size_t)(win * 300 + e) * 2048 + hb * 64 + hh];
    tile[kk][hh] = v;
  }
  __syncthreads();
  int kk = threadIdx.x & 63;
  int hq = threadIdx.x >> 6;
#pragma unroll
  for (int h = hq; h < 64; h += 4) {
    W1bT[(size_t)(hb * 64 + h) * 1600 + kb * 64 + kk] = f2bf(tile[kk][h]);
  }
}

// ---------- kernel 2: gather embeddings -> P bf16 [64][516][320] ----------
__global__ __launch_bounds__(320) void gather_kernel(
    const int* __restrict__ idxs, const float* __restrict__ emb,
    unsigned short* __restrict__ P) {
  int g = blockIdx.x;   // b*516 + tp
  int b = g / 516;
  int tp = g - b * 516;
  int tok = 0;
  if (tp >= 2 && tp < 514) tok = idxs[b * 512 + tp - 2];
  int e = threadIdx.x;
  float v = (e < 300) ? emb[(size_t)tok * 300 + e] : 0.f;
  P[(size_t)g * 320 + e] = f2bf(v);
}

// ---------- kernel 3: GEMM  Z[b*512+t][h] = sum_k A * W1bT + b1[h]  (bf16, f32 acc) ----------
__global__ __launch_bounds__(256) void gemm_kernel(
    const unsigned short* __restrict__ P,
    const unsigned short* __restrict__ W1bT,
    const float* __restrict__ b1,
    unsigned short* __restrict__ Z) {
  __shared__ unsigned short As[128 * 64];  // [row][k] 16KB
  __shared__ unsigned short Bs[128 * 64];  // [col][k] 16KB
  const int tid = threadIdx.x;
  const int lane = tid & 63;
  const int w = tid >> 6;
  const int wm = w >> 1, wn = w & 1;
  const int lr = lane & 15;
  const int lk = (lane >> 4) << 3;

  const int nt = blockIdx.x & 15;   // 2048/128
  const int mt = blockIdx.x >> 4;   // 32768/128
  const int b = mt >> 2;            // 4 tiles per batch
  const int t0 = (mt & 3) << 7;

  f32x4 acc[4][4];
#pragma unroll
  for (int i = 0; i < 4; i++)
#pragma unroll
    for (int j = 0; j < 4; j++) acc[i][j] = (f32x4){0.f, 0.f, 0.f, 0.f};

  for (int kt = 0; kt < 25; ++kt) {
    const int win = kt / 5;
    const int e0 = (kt % 5) << 6;
#pragma unroll
    for (int j = 0; j < 4; ++j) {
      int chunk = tid + j * 256;
      int row = chunk >> 3, kb = chunk & 7;
      const unsigned short* src =
          P + (size_t)(b * 516 + t0 + row + win) * 320 + e0 + (kb << 3);
      __builtin_amdgcn_global_load_lds(
          (const __attribute__((address_space(1))) unsigned int*)src,
          (__attribute__((address_space(3))) unsigned int*)&As[chunk << 3],
          16, 0, 0);
    }
#pragma unroll
    for (int j = 0; j < 4; ++j) {
      int chunk = tid + j * 256;
      int col = chunk >> 3, kb = chunk & 7;
      const unsigned short* src =
          W1bT + (size_t)(nt * 128 + col) * 1600 + (kt << 6) + (kb << 3);
      __builtin_amdgcn_global_load_lds(
          (const __attribute__((address_space(1))) unsigned int*)src,
          (__attribute__((address_space(3))) unsigned int*)&Bs[chunk << 3],
          16, 0, 0);
    }
    __syncthreads();
#pragma unroll
    for (int ks = 0; ks < 64; ks += 32) {
      bf16x8 af[4], bv[4];
#pragma unroll
      for (int am = 0; am < 4; ++am)
        af[am] = *(const bf16x8*)&As[((wm << 6) + (am << 4) + lr) * 64 + ks + lk];
#pragma unroll
      for (int bn = 0; bn < 4; ++bn)
        bv[bn] = *(const bf16x8*)&Bs[((wn << 6) + (bn << 4) + lr) * 64 + ks + lk];
#pragma unroll
      for (int am = 0; am < 4; ++am)
#pragma unroll
        for (int bn = 0; bn < 4; ++bn)
          acc[am][bn] = __builtin_amdgcn_mfma_f32_16x16x32_bf16(
              af[am], bv[bn], acc[am][bn], 0, 0, 0);
    }
    __syncthreads();
  }

  const int rbase = mt * 128 + (wm << 6) + ((lane >> 4) << 2);
  const int cbase = nt * 128 + (wn << 6) + lr;
  float b1v[4];
#pragma unroll
  for (int bn = 0; bn < 4; ++bn) b1v[bn] = b1[cbase + (bn << 4)];
#pragma unroll
  for (int am = 0; am < 4; ++am)
#pragma unroll
    for (int bn = 0; bn < 4; ++bn)
#pragma unroll
      for (int j = 0; j < 4; ++j) {
        int r = rbase + (am << 4) + j;
        int c = cbase + (bn << 4);
        Z[(size_t)r * 2048 + c] = f2bf(acc[am][bn][j] + b1v[bn]);
      }
}

// ---------- kernel 4: sequential scan, one block (8 waves) per batch ----------
// thread tid owns h = tid*4 .. tid*4+3 (two f32x2 pairs -> v_pk_fma_f32).
// prev state lives in registers (uniform across threads; softmax redundant).
__global__ __launch_bounds__(512, 1) void scan_kernel(
    const unsigned short* __restrict__ Z, const float* __restrict__ W1,
    const float* __restrict__ W2, const float* __restrict__ b2,
    const float* __restrict__ istate, float* __restrict__ out) {
  const int b = blockIdx.x;
  const int tid = threadIdx.x;
  const int lane = tid & 63;
  const int wv = tid >> 6;  // 0..7
  const unsigned short* Zb = Z + (size_t)b * 512 * 2048;
  float* outb = out + (size_t)b * 512 * 5;

  // per-thread weight registers: two h-pairs
  f32x2 wA[10], wB[10];
#pragma unroll
  for (int i = 0; i < 10; ++i) {
    const float* row = &W1[(size_t)(1500 + i) * 2048 + tid * 4];
    wA[i] = *(const f32x2*)&row[0];
    wB[i] = *(const f32x2*)&row[2];
  }
  f32x2 w2A[5], w2B[5];
#pragma unroll
  for (int k = 0; k < 5; ++k) {
    w2A[k] = (f32x2){W2[(tid * 4 + 0) * 5 + k], W2[(tid * 4 + 1) * 5 + k]};
    w2B[k] = (f32x2){W2[(tid * 4 + 2) * 5 + k], W2[(tid * 4 + 3) * 5 + k]};
  }
  const float b20 = b2[0], b21 = b2[1], b22 = b2[2], b23 = b2[3],
              b24 = b2[4];

  // recurrent state in registers (uniform across threads)
  float p0 = istate[0], p1 = istate[1], p2 = istate[2], p3 = istate[3],
        p4 = istate[4], p5 = istate[5], p6 = istate[6], p7 = istate[7],
        p8 = istate[8], p9 = istate[9];

  __shared__ float part[2][8][8];  // [parity][wave][k(padded to 8)]

  // software pipeline: prefetch distance 2 on the Z row (4 bf16 = 8B/lane)
  u16x4 zc = *(const u16x4*)&Zb[tid * 4];
  u16x4 zn = *(const u16x4*)&Zb[(size_t)2048 + tid * 4];

  for (int t = 0; t < 512; ++t) {
    // ---- stage A: two packed h-pairs ----
    f32x2 xA = (f32x2){bf2f(zc[0]), bf2f(zc[1])};  // z already contains b1
    f32x2 xB = (f32x2){bf2f(zc[2]), bf2f(zc[3])};
    xA = p0 * wA[0] + xA;  xB = p0 * wB[0] + xB;
    xA = p1 * wA[1] + xA;  xB = p1 * wB[1] + xB;
    xA = p2 * wA[2] + xA;  xB = p2 * wB[2] + xB;
    xA = p3 * wA[3] + xA;  xB = p3 * wB[3] + xB;
    xA = p4 * wA[4] + xA;  xB = p4 * wB[4] + xB;
    xA = p5 * wA[5] + xA;  xB = p5 * wB[5] + xB;
    xA = p6 * wA[6] + xA;  xB = p6 * wB[6] + xB;
    xA = p7 * wA[7] + xA;  xB = p7 * wB[7] + xB;
    xA = p8 * wA[8] + xA;  xB = p8 * wB[8] + xB;
    xA = p9 * wA[9] + xA;  xB = p9 * wB[9] + xB;
    xA = __builtin_elementwise_max(xA, (f32x2){0.f, 0.f});
    xB = __builtin_elementwise_max(xB, (f32x2){0.f, 0.f});
    f32x2 ya0 = xA * w2A[0] + xB * w2B[0];
    f32x2 ya1 = xA * w2A[1] + xB * w2B[1];
    f32x2 ya2 = xA * w2A[2] + xB * w2B[2];
    f32x2 ya3 = xA * w2A[3] + xB * w2B[3];
    f32x2 ya4 = xA * w2A[4] + xB * w2B[4];
    float y0 = ya0.x + ya0.y, y1 = ya1.x + ya1.y, y2 = ya2.x + ya2.y,
          y3 = ya3.x + ya3.y, y4 = ya4.x + ya4.y;

    // issue prefetch for t+2 (clamped; covers L3/HBM latency across 2 steps)
    int tn = (t + 2 < 512) ? (t + 2) : 511;
    u16x4 zf = *(const u16x4*)&Zb[(size_t)tn * 2048 + tid * 4];

    // ---- intra-wave reduce on the VALU pipe (DPP), sum lands in lane 63 ----
    y0 = wave_sum63(y0);
    y1 = wave_sum63(y1);
    y2 = wave_sum63(y2);
    y3 = wave_sum63(y3);
    y4 = wave_sum63(y4);
    const int pp = t & 1;
    if (lane == 63) {
      *(float4*)&part[pp][wv][0] = (float4){y0, y1, y2, y3};
      part[pp][wv][4] = y4;
    }
    __syncthreads();

    // ---- stage B: redundant final reduce + softmax on every thread ----
    float4 q0 = *(const float4*)&part[pp][0][0];
    float4 q1 = *(const float4*)&part[pp][1][0];
    float4 q2 = *(const float4*)&part[pp][2][0];
    float4 q3 = *(const float4*)&part[pp][3][0];
    float4 q4 = *(const float4*)&part[pp][4][0];
    float4 q5 = *(const float4*)&part[pp][5][0];
    float4 q6 = *(const float4*)&part[pp][6][0];
    float4 q7 = *(const float4*)&part[pp][7][0];
    float s0 = b20 + (((q0.x + q1.x) + (q2.x + q3.x)) +
                      ((q4.x + q5.x) + (q6.x + q7.x)));
    float s1 = b21 + (((q0.y + q1.y) + (q2.y + q3.y)) +
                      ((q4.y + q5.y) + (q6.y + q7.y)));
    float s2 = b22 + (((q0.z + q1.z) + (q2.z + q3.z)) +
                      ((q4.z + q5.z) + (q6.z + q7.z)));
    float s3 = b23 + (((q0.w + q1.w) + (q2.w + q3.w)) +
                      ((q4.w + q5.w) + (q6.w + q7.w)));
    float s4 = b24 + (((part[pp][0][4] + part[pp][1][4]) +
                       (part[pp][2][4] + part[pp][3][4])) +
                      ((part[pp][4][4] + part[pp][5][4]) +
                       (part[pp][6][4] + part[pp][7][4])));

    if (tid < 5) {  // 20B store of the 5 logits
      float v = s0;
      v = (tid == 1) ? s1 : v;
      v = (tid == 2) ? s2 : v;
      v = (tid == 3) ? s3 : v;
      v = (tid == 4) ? s4 : v;
      outb[t * 5 + tid] = v;
    }

    float m = fmaxf(fmaxf(fmaxf(s0, s1), fmaxf(s2, s3)), s4);
    float e0 = __expf(s0 - m), e1 = __expf(s1 - m), e2 = __expf(s2 - m),
          e3 = __expf(s3 - m), e4 = __expf(s4 - m);
    float d = ((e0 + e1) + (e2 + e3)) + e4;
    float rd = __builtin_amdgcn_rcpf(d);
    p0 = p5; p1 = p6; p2 = p7; p3 = p8; p4 = p9;
    p5 = e0 * rd; p6 = e1 * rd; p7 = e2 * rd; p8 = e3 * rd; p9 = e4 * rd;

    zc = zn; zn = zf;
    // no second barrier: next step writes part[pp^1]; the step-(t+1) barrier
    // orders those writes against this step's reads of part[pp].
  }
}

// ---------- launcher ----------
extern "C" void kernel_launch(void* const* d_in, const int* in_sizes, int n_in,
                              void* d_out, int out_size, void* d_ws,
                              size_t ws_size, hipStream_t stream) {
  const int* idxs = (const int*)d_in[0];
  const float* emb = (const float*)d_in[1];
  const float* W1 = (const float*)d_in[2];
  const float* b1 = (const float*)d_in[3];
  const float* W2 = (const float*)d_in[4];
  const float* b2 = (const float*)d_in[5];
  const float* istate = (const float*)d_in[6];
  float* out = (float*)d_out;

  char* ws = (char*)d_ws;
  unsigned short* P = (unsigned short*)ws;                          // 21,135,360 B
  unsigned short* W1bT = (unsigned short*)(ws + 21135360);          // 6,553,600 B
  unsigned short* Z = (unsigned short*)(ws + 21135360 + 6553600);   // 134,217,728 B

  hipLaunchKernelGGL(prepw1_kernel, dim3(25 * 32), dim3(256), 0, stream, W1, W1bT);
  hipLaunchKernelGGL(gather_kernel, dim3(64 * 516), dim3(320), 0, stream, idxs, emb, P);
  hipLaunchKernelGGL(gemm_kernel, dim3(256 * 16), dim3(256), 0, stream, P, W1bT, b1, Z);
  hipLaunchKernelGGL(scan_kernel, dim3(64), dim3(512), 0, stream, Z, W1, W2, b2,
                     istate, out);
}

// Round 10
// 608.760 us; speedup vs baseline: 1.1724x; 1.1724x over previous
//
#include <hip/hip_runtime.h>

// ---------- types ----------
typedef __attribute__((ext_vector_type(8))) short bf16x8;
typedef __attribute__((ext_vector_type(8))) unsigned short u16x8;
typedef __attribute__((ext_vector_type(4))) float f32x4;
typedef __attribute__((ext_vector_type(2))) float f32x2;

__device__ __forceinline__ unsigned short f2bf(float f) {
  union { float f; unsigned u; } v; v.f = f;
  unsigned r = v.u + 0x7FFFu + ((v.u >> 16) & 1u);
  return (unsigned short)(r >> 16);
}
__device__ __forceinline__ float bf2f(unsigned short s) {
  union { unsigned u; float f; } v; v.u = ((unsigned)s) << 16;
  return v.f;
}

// DPP-based wave64 sum; result valid in lane 63 only.
template <int CTRL>
__device__ __forceinline__ float dpp_add(float v) {
  int m = __builtin_amdgcn_update_dpp(0, __float_as_int(v), CTRL, 0xf, 0xf, true);
  return v + __int_as_float(m);
}
__device__ __forceinline__ float wave_sum63(float v) {
  v = dpp_add<0x111>(v);  // row_shr:1
  v = dpp_add<0x112>(v);  // row_shr:2
  v = dpp_add<0x114>(v);  // row_shr:4
  v = dpp_add<0x118>(v);  // row_shr:8  -> lane15 of each row has row sum
  v = dpp_add<0x142>(v);  // row_bcast:15
  v = dpp_add<0x143>(v);  // row_bcast:31 -> lane63 has wave sum
  return v;
}

// Problem constants
// B=64 T=512 E=300 V=50000 H=2048 WP=2 OUT=5
// padded: EP=320, TP=516, KP=1600, M=B*T=32768

// ---------- kernel 1: W1 -> W1bT bf16 [2048][1600] (transposed, K-padded) ----------
__global__ __launch_bounds__(256) void prepw1_kernel(
    const float* __restrict__ W1, unsigned short* __restrict__ W1bT) {
  __shared__ float tile[64][65];
  int kb = blockIdx.x % 25;   // K tile (padded K = 1600 = 25*64)
  int hb = blockIdx.x / 25;   // H tile (2048 = 32*64)
  int win = kb / 5;
  int e0 = (kb % 5) << 6;
  int hh = threadIdx.x & 63;
  int kq = threadIdx.x >> 6;
#pragma unroll
  for (int kk = kq; kk < 64; kk += 4) {
    int e = e0 + kk;
    float v = 0.f;
    if (e < 300) v = W1[(size_t)(win * 300 + e) * 2048 + hb * 64 + hh];
    tile[kk][hh] = v;
  }
  __syncthreads();
  int kk = threadIdx.x & 63;
  int hq = threadIdx.x >> 6;
#pragma unroll
  for (int h = hq; h < 64; h += 4) {
    W1bT[(size_t)(hb * 64 + h) * 1600 + kb * 64 + kk] = f2bf(tile[kk][h]);
  }
}

// ---------- kernel 2: gather embeddings -> P bf16 [64][516][320] ----------
__global__ __launch_bounds__(320) void gather_kernel(
    const int* __restrict__ idxs, const float* __restrict__ emb,
    unsigned short* __restrict__ P) {
  int g = blockIdx.x;   // b*516 + tp
  int b = g / 516;
  int tp = g - b * 516;
  int tok = 0;
  if (tp >= 2 && tp < 514) tok = idxs[b * 512 + tp - 2];
  int e = threadIdx.x;
  float v = (e < 300) ? emb[(size_t)tok * 300 + e] : 0.f;
  P[(size_t)g * 320 + e] = f2bf(v);
}

// ---------- kernel 3: GEMM  Z[b*512+t][h] = sum_k A * W1bT + b1[h]  (bf16, f32 acc) ----------
__global__ __launch_bounds__(256) void gemm_kernel(
    const unsigned short* __restrict__ P,
    const unsigned short* __restrict__ W1bT,
    const float* __restrict__ b1,
    unsigned short* __restrict__ Z) {
  __shared__ unsigned short As[128 * 64];  // [row][k] 16KB
  __shared__ unsigned short Bs[128 * 64];  // [col][k] 16KB
  const int tid = threadIdx.x;
  const int lane = tid & 63;
  const int w = tid >> 6;
  const int wm = w >> 1, wn = w & 1;
  const int lr = lane & 15;
  const int lk = (lane >> 4) << 3;

  const int nt = blockIdx.x & 15;   // 2048/128
  const int mt = blockIdx.x >> 4;   // 32768/128
  const int b = mt >> 2;            // 4 tiles per batch
  const int t0 = (mt & 3) << 7;

  f32x4 acc[4][4];
#pragma unroll
  for (int i = 0; i < 4; i++)
#pragma unroll
    for (int j = 0; j < 4; j++) acc[i][j] = (f32x4){0.f, 0.f, 0.f, 0.f};

  for (int kt = 0; kt < 25; ++kt) {
    const int win = kt / 5;
    const int e0 = (kt % 5) << 6;
#pragma unroll
    for (int j = 0; j < 4; ++j) {
      int chunk = tid + j * 256;
      int row = chunk >> 3, kb = chunk & 7;
      const unsigned short* src =
          P + (size_t)(b * 516 + t0 + row + win) * 320 + e0 + (kb << 3);
      __builtin_amdgcn_global_load_lds(
          (const __attribute__((address_space(1))) unsigned int*)src,
          (__attribute__((address_space(3))) unsigned int*)&As[chunk << 3],
          16, 0, 0);
    }
#pragma unroll
    for (int j = 0; j < 4; ++j) {
      int chunk = tid + j * 256;
      int col = chunk >> 3, kb = chunk & 7;
      const unsigned short* src =
          W1bT + (size_t)(nt * 128 + col) * 1600 + (kt << 6) + (kb << 3);
      __builtin_amdgcn_global_load_lds(
          (const __attribute__((address_space(1))) unsigned int*)src,
          (__attribute__((address_space(3))) unsigned int*)&Bs[chunk << 3],
          16, 0, 0);
    }
    __syncthreads();
#pragma unroll
    for (int ks = 0; ks < 64; ks += 32) {
      bf16x8 af[4], bv[4];
#pragma unroll
      for (int am = 0; am < 4; ++am)
        af[am] = *(const bf16x8*)&As[((wm << 6) + (am << 4) + lr) * 64 + ks + lk];
#pragma unroll
      for (int bn = 0; bn < 4; ++bn)
        bv[bn] = *(const bf16x8*)&Bs[((wn << 6) + (bn << 4) + lr) * 64 + ks + lk];
#pragma unroll
      for (int am = 0; am < 4; ++am)
#pragma unroll
        for (int bn = 0; bn < 4; ++bn)
          acc[am][bn] = __builtin_amdgcn_mfma_f32_16x16x32_bf16(
              af[am], bv[bn], acc[am][bn], 0, 0, 0);
    }
    __syncthreads();
  }

  const int rbase = mt * 128 + (wm << 6) + ((lane >> 4) << 2);
  const int cbase = nt * 128 + (wn << 6) + lr;
  float b1v[4];
#pragma unroll
  for (int bn = 0; bn < 4; ++bn) b1v[bn] = b1[cbase + (bn << 4)];
#pragma unroll
  for (int am = 0; am < 4; ++am)
#pragma unroll
    for (int bn = 0; bn < 4; ++bn)
#pragma unroll
      for (int j = 0; j < 4; ++j) {
        int r = rbase + (am << 4) + j;
        int c = cbase + (bn << 4);
        Z[(size_t)r * 2048 + c] = f2bf(acc[am][bn][j] + b1v[bn]);
      }
}

// ---------- kernel 4: sequential scan, one block (4 waves) per batch ----------
// thread tid owns h = tid*8 .. tid*8+7 (four f32x2 pairs).
// prev state in registers (uniform across threads; stage B redundant per
// thread).  NO __syncthreads in the loop: raw s_barrier + lgkmcnt(0) only,
// so Z prefetch loads stay in flight across barriers (counted vmcnt).
// No stores in the loop: thread tid latches logits of steps 2t,2t+1 into
// registers and writes 40B once at the end.
__global__ __launch_bounds__(256, 1) void scan_kernel(
    const unsigned short* __restrict__ Z, const float* __restrict__ W1,
    const float* __restrict__ W2, const float* __restrict__ b2,
    const float* __restrict__ istate, float* __restrict__ out) {
  const int b = blockIdx.x;
  const int tid = threadIdx.x;
  const int lane = tid & 63;
  const int wv = tid >> 6;  // 0..3
  const unsigned short* Zb = Z + (size_t)b * 512 * 2048;
  float* outb = out + (size_t)b * 512 * 5;

  // per-thread weight registers: four h-pairs, packed
  f32x2 w1p[4][10];
#pragma unroll
  for (int i = 0; i < 10; ++i) {
    const float* row = &W1[(size_t)(1500 + i) * 2048 + tid * 8];
#pragma unroll
    for (int q = 0; q < 4; ++q) w1p[q][i] = *(const f32x2*)&row[q * 2];
  }
  f32x2 w2p[4][5];
#pragma unroll
  for (int k = 0; k < 5; ++k)
#pragma unroll
    for (int q = 0; q < 4; ++q)
      w2p[q][k] = (f32x2){W2[(tid * 8 + 2 * q) * 5 + k],
                          W2[(tid * 8 + 2 * q + 1) * 5 + k]};
  const float b20 = b2[0], b21 = b2[1], b22 = b2[2], b23 = b2[3],
              b24 = b2[4];

  // recurrent state in registers (uniform across threads)
  float pr[10];
#pragma unroll
  for (int i = 0; i < 10; ++i) pr[i] = istate[i];

  __shared__ float part[2][4][8];  // [parity][wave][k(padded to 8)]

  // output latch registers: this thread owns steps tA=2*tid, tB=2*tid+1
  const int tA = tid * 2, tB = tid * 2 + 1;
  float o[10];
#pragma unroll
  for (int i = 0; i < 10; ++i) o[i] = 0.f;

  // software pipeline: prefetch distance 2 on the Z row (8 bf16 = 16B/lane)
  u16x8 zc = *(const u16x8*)&Zb[tid * 8];
  u16x8 zn = *(const u16x8*)&Zb[(size_t)2048 + tid * 8];

  for (int t = 0; t < 512; ++t) {
    // ---- stage A: four packed h-pairs ----
    f32x2 x0 = (f32x2){bf2f(zc[0]), bf2f(zc[1])};  // z already contains b1
    f32x2 x1 = (f32x2){bf2f(zc[2]), bf2f(zc[3])};
    f32x2 x2 = (f32x2){bf2f(zc[4]), bf2f(zc[5])};
    f32x2 x3 = (f32x2){bf2f(zc[6]), bf2f(zc[7])};
#pragma unroll
    for (int i = 0; i < 10; ++i) {
      const float pi = pr[i];
      x0 = pi * w1p[0][i] + x0;
      x1 = pi * w1p[1][i] + x1;
      x2 = pi * w1p[2][i] + x2;
      x3 = pi * w1p[3][i] + x3;
    }
    const f32x2 zero2 = (f32x2){0.f, 0.f};
    x0 = __builtin_elementwise_max(x0, zero2);
    x1 = __builtin_elementwise_max(x1, zero2);
    x2 = __builtin_elementwise_max(x2, zero2);
    x3 = __builtin_elementwise_max(x3, zero2);
    f32x2 a0 = x0 * w2p[0][0] + x1 * w2p[1][0];
    f32x2 a1 = x0 * w2p[0][1] + x1 * w2p[1][1];
    f32x2 a2 = x0 * w2p[0][2] + x1 * w2p[1][2];
    f32x2 a3 = x0 * w2p[0][3] + x1 * w2p[1][3];
    f32x2 a4 = x0 * w2p[0][4] + x1 * w2p[1][4];
    a0 = x2 * w2p[2][0] + a0;  a0 = x3 * w2p[3][0] + a0;
    a1 = x2 * w2p[2][1] + a1;  a1 = x3 * w2p[3][1] + a1;
    a2 = x2 * w2p[2][2] + a2;  a2 = x3 * w2p[3][2] + a2;
    a3 = x2 * w2p[2][3] + a3;  a3 = x3 * w2p[3][3] + a3;
    a4 = x2 * w2p[2][4] + a4;  a4 = x3 * w2p[3][4] + a4;
    float y0 = a0.x + a0.y, y1 = a1.x + a1.y, y2 = a2.x + a2.y,
          y3 = a3.x + a3.y, y4 = a4.x + a4.y;

    // issue prefetch for t+2 (stays in flight across the raw barrier)
    int tn = (t + 2 < 512) ? (t + 2) : 511;
    u16x8 zf = *(const u16x8*)&Zb[(size_t)tn * 2048 + tid * 8];

    // ---- intra-wave reduce on the VALU pipe (DPP), sum lands in lane 63 ----
    y0 = wave_sum63(y0);
    y1 = wave_sum63(y1);
    y2 = wave_sum63(y2);
    y3 = wave_sum63(y3);
    y4 = wave_sum63(y4);
    const int pp = t & 1;
    if (lane == 63) {
      *(float4*)&part[pp][wv][0] = (float4){y0, y1, y2, y3};
      part[pp][wv][4] = y4;
    }
    // raw barrier: drain LDS only (NOT vmcnt -> Z prefetch stays in flight)
    asm volatile("s_waitcnt lgkmcnt(0)" ::: "memory");
    __builtin_amdgcn_sched_barrier(0);
    __builtin_amdgcn_s_barrier();
    __builtin_amdgcn_sched_barrier(0);

    // ---- stage B: redundant final reduce + softmax on every thread ----
    float4 q0 = *(const float4*)&part[pp][0][0];
    float4 q1 = *(const float4*)&part[pp][1][0];
    float4 q2 = *(const float4*)&part[pp][2][0];
    float4 q3 = *(const float4*)&part[pp][3][0];
    float s0 = b20 + ((q0.x + q1.x) + (q2.x + q3.x));
    float s1 = b21 + ((q0.y + q1.y) + (q2.y + q3.y));
    float s2 = b22 + ((q0.z + q1.z) + (q2.z + q3.z));
    float s3 = b23 + ((q0.w + q1.w) + (q2.w + q3.w));
    float s4 = b24 + ((part[pp][0][4] + part[pp][1][4]) +
                      (part[pp][2][4] + part[pp][3][4]));

    // latch this thread's two output steps into registers (no stores in loop)
    const bool selA = (t == tA), selB = (t == tB);
    o[0] = selA ? s0 : o[0];
    o[1] = selA ? s1 : o[1];
    o[2] = selA ? s2 : o[2];
    o[3] = selA ? s3 : o[3];
    o[4] = selA ? s4 : o[4];
    o[5] = selB ? s0 : o[5];
    o[6] = selB ? s1 : o[6];
    o[7] = selB ? s2 : o[7];
    o[8] = selB ? s3 : o[8];
    o[9] = selB ? s4 : o[9];

    float m = fmaxf(fmaxf(fmaxf(s0, s1), fmaxf(s2, s3)), s4);
    float e0 = __expf(s0 - m), e1 = __expf(s1 - m), e2 = __expf(s2 - m),
          e3 = __expf(s3 - m), e4 = __expf(s4 - m);
    float d = ((e0 + e1) + (e2 + e3)) + e4;
    float rd = __builtin_amdgcn_rcpf(d);
    pr[0] = pr[5]; pr[1] = pr[6]; pr[2] = pr[7]; pr[3] = pr[8]; pr[4] = pr[9];
    pr[5] = e0 * rd; pr[6] = e1 * rd; pr[7] = e2 * rd; pr[8] = e3 * rd;
    pr[9] = e4 * rd;

    zc = zn; zn = zf;
  }

  // final coalesced store: thread tid -> out[b][tid*10 .. tid*10+10)
  float* dst = outb + tid * 10;
#pragma unroll
  for (int i = 0; i < 10; ++i) dst[i] = o[i];
}

// ---------- launcher ----------
extern "C" void kernel_launch(void* const* d_in, const int* in_sizes, int n_in,
                              void* d_out, int out_size, void* d_ws,
                              size_t ws_size, hipStream_t stream) {
  const int* idxs = (const int*)d_in[0];
  const float* emb = (const float*)d_in[1];
  const float* W1 = (const float*)d_in[2];
  const float* b1 = (const float*)d_in[3];
  const float* W2 = (const float*)d_in[4];
  const float* b2 = (const float*)d_in[5];
  const float* istate = (const float*)d_in[6];
  float* out = (float*)d_out;

  char* ws = (char*)d_ws;
  unsigned short* P = (unsigned short*)ws;                          // 21,135,360 B
  unsigned short* W1bT = (unsigned short*)(ws + 21135360);          // 6,553,600 B
  unsigned short* Z = (unsigned short*)(ws + 21135360 + 6553600);   // 134,217,728 B

  hipLaunchKernelGGL(prepw1_kernel, dim3(25 * 32), dim3(256), 0, stream, W1, W1bT);
  hipLaunchKernelGGL(gather_kernel, dim3(64 * 516), dim3(320), 0, stream, idxs, emb, P);
  hipLaunchKernelGGL(gemm_kernel, dim3(256 * 16), dim3(256), 0, stream, P, W1bT, b1, Z);
  hipLaunchKernelGGL(scan_kernel, dim3(64), dim3(256), 0, stream, Z, W1, W2, b2,
                     istate, out);
}

// Round 11
// 552.768 us; speedup vs baseline: 1.2911x; 1.1013x over previous
//
#include <hip/hip_runtime.h>

// ---------- types ----------
typedef __attribute__((ext_vector_type(8))) short bf16x8;
typedef __attribute__((ext_vector_type(8))) unsigned short u16x8;
typedef __attribute__((ext_vector_type(4))) float f32x4;
typedef __attribute__((ext_vector_type(2))) float f32x2;

__device__ __forceinline__ unsigned short f2bf(float f) {
  union { float f; unsigned u; } v; v.f = f;
  unsigned r = v.u + 0x7FFFu + ((v.u >> 16) & 1u);
  return (unsigned short)(r >> 16);
}
__device__ __forceinline__ float bf2f(unsigned short s) {
  union { unsigned u; float f; } v; v.u = ((unsigned)s) << 16;
  return v.f;
}

// DPP-based wave64 sum; result valid in lane 63 only.
template <int CTRL>
__device__ __forceinline__ float dpp_add(float v) {
  int m = __builtin_amdgcn_update_dpp(0, __float_as_int(v), CTRL, 0xf, 0xf, true);
  return v + __int_as_float(m);
}
__device__ __forceinline__ float wave_sum63(float v) {
  v = dpp_add<0x111>(v);  // row_shr:1
  v = dpp_add<0x112>(v);  // row_shr:2
  v = dpp_add<0x114>(v);  // row_shr:4
  v = dpp_add<0x118>(v);  // row_shr:8  -> lane15 of each row has row sum
  v = dpp_add<0x142>(v);  // row_bcast:15
  v = dpp_add<0x143>(v);  // row_bcast:31 -> lane63 has wave sum
  return v;
}

// Problem constants
// B=64 T=512 E=300 V=50000 H=2048 WP=2 OUT=5
// padded: EP=320, TP=516, KP=1600, M=B*T=32768

// ---------- kernel 1: W1 -> W1bT bf16 [2048][1600] (transposed, K-padded) ----------
__global__ __launch_bounds__(256) void prepw1_kernel(
    const float* __restrict__ W1, unsigned short* __restrict__ W1bT) {
  __shared__ float tile[64][65];
  int kb = blockIdx.x % 25;   // K tile (padded K = 1600 = 25*64)
  int hb = blockIdx.x / 25;   // H tile (2048 = 32*64)
  int win = kb / 5;
  int e0 = (kb % 5) << 6;
  int hh = threadIdx.x & 63;
  int kq = threadIdx.x >> 6;
#pragma unroll
  for (int kk = kq; kk < 64; kk += 4) {
    int e = e0 + kk;
    float v = 0.f;
    if (e < 300) v = W1[(size_t)(win * 300 + e) * 2048 + hb * 64 + hh];
    tile[kk][hh] = v;
  }
  __syncthreads();
  int kk = threadIdx.x & 63;
  int hq = threadIdx.x >> 6;
#pragma unroll
  for (int h = hq; h < 64; h += 4) {
    W1bT[(size_t)(hb * 64 + h) * 1600 + kb * 64 + kk] = f2bf(tile[kk][h]);
  }
}

// ---------- kernel 2: gather embeddings -> P bf16 [64][516][320] ----------
__global__ __launch_bounds__(320) void gather_kernel(
    const int* __restrict__ idxs, const float* __restrict__ emb,
    unsigned short* __restrict__ P) {
  int g = blockIdx.x;   // b*516 + tp
  int b = g / 516;
  int tp = g - b * 516;
  int tok = 0;
  if (tp >= 2 && tp < 514) tok = idxs[b * 512 + tp - 2];
  int e = threadIdx.x;
  float v = (e < 300) ? emb[(size_t)tok * 300 + e] : 0.f;
  P[(size_t)g * 320 + e] = f2bf(v);
}

// ---------- kernel 3: GEMM  Z[b*512+t][h] = sum_k A * W1bT + b1[h]  (bf16, f32 acc) ----------
// T2 bank-conflict fix (both-sides swizzle, rule #21): LDS dest stays linear;
// the global SOURCE of 16B chunk (row,kb) is pre-swizzled to (row, kb^(row&7));
// the ds_read XORs the same involution back in.  Data bitwise identical.
__global__ __launch_bounds__(256) void gemm_kernel(
    const unsigned short* __restrict__ P,
    const unsigned short* __restrict__ W1bT,
    const float* __restrict__ b1,
    unsigned short* __restrict__ Z) {
  __shared__ unsigned short As[128 * 64];  // [row][k] 16KB (swizzled slots)
  __shared__ unsigned short Bs[128 * 64];  // [col][k] 16KB (swizzled slots)
  const int tid = threadIdx.x;
  const int lane = tid & 63;
  const int w = tid >> 6;
  const int wm = w >> 1, wn = w & 1;
  const int lr = lane & 15;
  const int lk = (lane >> 4) << 3;

  const int nt = blockIdx.x & 15;   // 2048/128
  const int mt = blockIdx.x >> 4;   // 32768/128
  const int b = mt >> 2;            // 4 tiles per batch
  const int t0 = (mt & 3) << 7;

  f32x4 acc[4][4];
#pragma unroll
  for (int i = 0; i < 4; i++)
#pragma unroll
    for (int j = 0; j < 4; j++) acc[i][j] = (f32x4){0.f, 0.f, 0.f, 0.f};

  for (int kt = 0; kt < 25; ++kt) {
    const int win = kt / 5;
    const int e0 = (kt % 5) << 6;
#pragma unroll
    for (int j = 0; j < 4; ++j) {
      int chunk = tid + j * 256;
      int row = chunk >> 3, kb = chunk & 7;
      int kbs = kb ^ (row & 7);  // pre-swizzled source slot
      const unsigned short* src =
          P + (size_t)(b * 516 + t0 + row + win) * 320 + e0 + (kbs << 3);
      __builtin_amdgcn_global_load_lds(
          (const __attribute__((address_space(1))) unsigned int*)src,
          (__attribute__((address_space(3))) unsigned int*)&As[chunk << 3],
          16, 0, 0);
    }
#pragma unroll
    for (int j = 0; j < 4; ++j) {
      int chunk = tid + j * 256;
      int col = chunk >> 3, kb = chunk & 7;
      int kbs = kb ^ (col & 7);  // pre-swizzled source slot
      const unsigned short* src =
          W1bT + (size_t)(nt * 128 + col) * 1600 + (kt << 6) + (kbs << 3);
      __builtin_amdgcn_global_load_lds(
          (const __attribute__((address_space(1))) unsigned int*)src,
          (__attribute__((address_space(3))) unsigned int*)&Bs[chunk << 3],
          16, 0, 0);
    }
    __syncthreads();
#pragma unroll
    for (int ks = 0; ks < 64; ks += 32) {
      const int slot = (ks + lk) >> 3;  // 16B slot index 0..7
      bf16x8 af[4], bv[4];
#pragma unroll
      for (int am = 0; am < 4; ++am) {
        int row = (wm << 6) + (am << 4) + lr;
        af[am] = *(const bf16x8*)&As[(row << 6) + ((slot ^ (row & 7)) << 3)];
      }
#pragma unroll
      for (int bn = 0; bn < 4; ++bn) {
        int col = (wn << 6) + (bn << 4) + lr;
        bv[bn] = *(const bf16x8*)&Bs[(col << 6) + ((slot ^ (col & 7)) << 3)];
      }
#pragma unroll
      for (int am = 0; am < 4; ++am)
#pragma unroll
        for (int bn = 0; bn < 4; ++bn)
          acc[am][bn] = __builtin_amdgcn_mfma_f32_16x16x32_bf16(
              af[am], bv[bn], acc[am][bn], 0, 0, 0);
    }
    __syncthreads();
  }

  const int rbase = mt * 128 + (wm << 6) + ((lane >> 4) << 2);
  const int cbase = nt * 128 + (wn << 6) + lr;
  float b1v[4];
#pragma unroll
  for (int bn = 0; bn < 4; ++bn) b1v[bn] = b1[cbase + (bn << 4)];
#pragma unroll
  for (int am = 0; am < 4; ++am)
#pragma unroll
    for (int bn = 0; bn < 4; ++bn)
#pragma unroll
      for (int j = 0; j < 4; ++j) {
        int r = rbase + (am << 4) + j;
        int c = cbase + (bn << 4);
        Z[(size_t)r * 2048 + c] = f2bf(acc[am][bn][j] + b1v[bn]);
      }
}

// ---------- kernel 4: sequential scan, one block (4 waves) per batch ----------
// thread tid owns h = tid*8 .. tid*8+7 (four f32x2 pairs).
// prev state in registers (uniform across threads; stage B redundant per
// thread).  NO __syncthreads in the loop: raw s_barrier + lgkmcnt(0) only,
// so Z prefetch loads stay in flight across barriers (counted vmcnt).
// No stores in the loop: thread tid latches logits of steps 2t,2t+1 into
// registers and writes 40B once at the end.
__global__ __launch_bounds__(256, 1) void scan_kernel(
    const unsigned short* __restrict__ Z, const float* __restrict__ W1,
    const float* __restrict__ W2, const float* __restrict__ b2,
    const float* __restrict__ istate, float* __restrict__ out) {
  const int b = blockIdx.x;
  const int tid = threadIdx.x;
  const int lane = tid & 63;
  const int wv = tid >> 6;  // 0..3
  const unsigned short* Zb = Z + (size_t)b * 512 * 2048;
  float* outb = out + (size_t)b * 512 * 5;

  // per-thread weight registers: four h-pairs, packed
  f32x2 w1p[4][10];
#pragma unroll
  for (int i = 0; i < 10; ++i) {
    const float* row = &W1[(size_t)(1500 + i) * 2048 + tid * 8];
#pragma unroll
    for (int q = 0; q < 4; ++q) w1p[q][i] = *(const f32x2*)&row[q * 2];
  }
  f32x2 w2p[4][5];
#pragma unroll
  for (int k = 0; k < 5; ++k)
#pragma unroll
    for (int q = 0; q < 4; ++q)
      w2p[q][k] = (f32x2){W2[(tid * 8 + 2 * q) * 5 + k],
                          W2[(tid * 8 + 2 * q + 1) * 5 + k]};
  const float b20 = b2[0], b21 = b2[1], b22 = b2[2], b23 = b2[3],
              b24 = b2[4];

  // recurrent state in registers (uniform across threads)
  float pr[10];
#pragma unroll
  for (int i = 0; i < 10; ++i) pr[i] = istate[i];

  __shared__ float part[2][4][8];  // [parity][wave][k(padded to 8)]

  // output latch registers: this thread owns steps tA=2*tid, tB=2*tid+1
  const int tA = tid * 2, tB = tid * 2 + 1;
  float o[10];
#pragma unroll
  for (int i = 0; i < 10; ++i) o[i] = 0.f;

  // software pipeline: prefetch distance 2 on the Z row (8 bf16 = 16B/lane)
  u16x8 zc = *(const u16x8*)&Zb[tid * 8];
  u16x8 zn = *(const u16x8*)&Zb[(size_t)2048 + tid * 8];

  for (int t = 0; t < 512; ++t) {
    // ---- stage A: four packed h-pairs ----
    f32x2 x0 = (f32x2){bf2f(zc[0]), bf2f(zc[1])};  // z already contains b1
    f32x2 x1 = (f32x2){bf2f(zc[2]), bf2f(zc[3])};
    f32x2 x2 = (f32x2){bf2f(zc[4]), bf2f(zc[5])};
    f32x2 x3 = (f32x2){bf2f(zc[6]), bf2f(zc[7])};
#pragma unroll
    for (int i = 0; i < 10; ++i) {
      const float pi = pr[i];
      x0 = pi * w1p[0][i] + x0;
      x1 = pi * w1p[1][i] + x1;
      x2 = pi * w1p[2][i] + x2;
      x3 = pi * w1p[3][i] + x3;
    }
    const f32x2 zero2 = (f32x2){0.f, 0.f};
    x0 = __builtin_elementwise_max(x0, zero2);
    x1 = __builtin_elementwise_max(x1, zero2);
    x2 = __builtin_elementwise_max(x2, zero2);
    x3 = __builtin_elementwise_max(x3, zero2);
    f32x2 a0 = x0 * w2p[0][0] + x1 * w2p[1][0];
    f32x2 a1 = x0 * w2p[0][1] + x1 * w2p[1][1];
    f32x2 a2 = x0 * w2p[0][2] + x1 * w2p[1][2];
    f32x2 a3 = x0 * w2p[0][3] + x1 * w2p[1][3];
    f32x2 a4 = x0 * w2p[0][4] + x1 * w2p[1][4];
    a0 = x2 * w2p[2][0] + a0;  a0 = x3 * w2p[3][0] + a0;
    a1 = x2 * w2p[2][1] + a1;  a1 = x3 * w2p[3][1] + a1;
    a2 = x2 * w2p[2][2] + a2;  a2 = x3 * w2p[3][2] + a2;
    a3 = x2 * w2p[2][3] + a3;  a3 = x3 * w2p[3][3] + a3;
    a4 = x2 * w2p[2][4] + a4;  a4 = x3 * w2p[3][4] + a4;
    float y0 = a0.x + a0.y, y1 = a1.x + a1.y, y2 = a2.x + a2.y,
          y3 = a3.x + a3.y, y4 = a4.x + a4.y;

    // issue prefetch for t+2 (stays in flight across the raw barrier)
    int tn = (t + 2 < 512) ? (t + 2) : 511;
    u16x8 zf = *(const u16x8*)&Zb[(size_t)tn * 2048 + tid * 8];

    // ---- intra-wave reduce on the VALU pipe (DPP), sum lands in lane 63 ----
    y0 = wave_sum63(y0);
    y1 = wave_sum63(y1);
    y2 = wave_sum63(y2);
    y3 = wave_sum63(y3);
    y4 = wave_sum63(y4);
    const int pp = t & 1;
    if (lane == 63) {
      *(float4*)&part[pp][wv][0] = (float4){y0, y1, y2, y3};
      part[pp][wv][4] = y4;
    }
    // raw barrier: drain LDS only (NOT vmcnt -> Z prefetch stays in flight)
    asm volatile("s_waitcnt lgkmcnt(0)" ::: "memory");
    __builtin_amdgcn_sched_barrier(0);
    __builtin_amdgcn_s_barrier();
    __builtin_amdgcn_sched_barrier(0);

    // ---- stage B: redundant final reduce + softmax on every thread ----
    float4 q0 = *(const float4*)&part[pp][0][0];
    float4 q1 = *(const float4*)&part[pp][1][0];
    float4 q2 = *(const float4*)&part[pp][2][0];
    float4 q3 = *(const float4*)&part[pp][3][0];
    float s0 = b20 + ((q0.x + q1.x) + (q2.x + q3.x));
    float s1 = b21 + ((q0.y + q1.y) + (q2.y + q3.y));
    float s2 = b22 + ((q0.z + q1.z) + (q2.z + q3.z));
    float s3 = b23 + ((q0.w + q1.w) + (q2.w + q3.w));
    float s4 = b24 + ((part[pp][0][4] + part[pp][1][4]) +
                      (part[pp][2][4] + part[pp][3][4]));

    // latch this thread's two output steps into registers (no stores in loop)
    const bool selA = (t == tA), selB = (t == tB);
    o[0] = selA ? s0 : o[0];
    o[1] = selA ? s1 : o[1];
    o[2] = selA ? s2 : o[2];
    o[3] = selA ? s3 : o[3];
    o[4] = selA ? s4 : o[4];
    o[5] = selB ? s0 : o[5];
    o[6] = selB ? s1 : o[6];
    o[7] = selB ? s2 : o[7];
    o[8] = selB ? s3 : o[8];
    o[9] = selB ? s4 : o[9];

    float m = fmaxf(fmaxf(fmaxf(s0, s1), fmaxf(s2, s3)), s4);
    float e0 = __expf(s0 - m), e1 = __expf(s1 - m), e2 = __expf(s2 - m),
          e3 = __expf(s3 - m), e4 = __expf(s4 - m);
    float d = ((e0 + e1) + (e2 + e3)) + e4;
    float rd = __builtin_amdgcn_rcpf(d);
    pr[0] = pr[5]; pr[1] = pr[6]; pr[2] = pr[7]; pr[3] = pr[8]; pr[4] = pr[9];
    pr[5] = e0 * rd; pr[6] = e1 * rd; pr[7] = e2 * rd; pr[8] = e3 * rd;
    pr[9] = e4 * rd;

    zc = zn; zn = zf;
  }

  // final coalesced store: thread tid -> out[b][tid*10 .. tid*10+10)
  float* dst = outb + tid * 10;
#pragma unroll
  for (int i = 0; i < 10; ++i) dst[i] = o[i];
}

// ---------- launcher ----------
extern "C" void kernel_launch(void* const* d_in, const int* in_sizes, int n_in,
                              void* d_out, int out_size, void* d_ws,
                              size_t ws_size, hipStream_t stream) {
  const int* idxs = (const int*)d_in[0];
  const float* emb = (const float*)d_in[1];
  const float* W1 = (const float*)d_in[2];
  const float* b1 = (const float*)d_in[3];
  const float* W2 = (const float*)d_in[4];
  const float* b2 = (const float*)d_in[5];
  const float* istate = (const float*)d_in[6];
  float* out = (float*)d_out;

  char* ws = (char*)d_ws;
  unsigned short* P = (unsigned short*)ws;                          // 21,135,360 B
  unsigned short* W1bT = (unsigned short*)(ws + 21135360);          // 6,553,600 B
  unsigned short* Z = (unsigned short*)(ws + 21135360 + 6553600);   // 134,217,728 B

  hipLaunchKernelGGL(prepw1_kernel, dim3(25 * 32), dim3(256), 0, stream, W1, W1bT);
  hipLaunchKernelGGL(gather_kernel, dim3(64 * 516), dim3(320), 0, stream, idxs, emb, P);
  hipLaunchKernelGGL(gemm_kernel, dim3(256 * 16), dim3(256), 0, stream, P, W1bT, b1, Z);
  hipLaunchKernelGGL(scan_kernel, dim3(64), dim3(256), 0, stream, Z, W1, W2, b2,
                     istate, out);
}

// Round 12
// 550.269 us; speedup vs baseline: 1.2970x; 1.0045x over previous
//
#include <hip/hip_runtime.h>

// ---------- types ----------
typedef __attribute__((ext_vector_type(8))) short bf16x8;
typedef __attribute__((ext_vector_type(8))) unsigned short u16x8;
typedef __attribute__((ext_vector_type(4))) float f32x4;
typedef __attribute__((ext_vector_type(2))) float f32x2;

__device__ __forceinline__ unsigned short f2bf(float f) {
  union { float f; unsigned u; } v; v.f = f;
  unsigned r = v.u + 0x7FFFu + ((v.u >> 16) & 1u);
  return (unsigned short)(r >> 16);
}
__device__ __forceinline__ float bf2f(unsigned short s) {
  union { unsigned u; float f; } v; v.u = ((unsigned)s) << 16;
  return v.f;
}

// DPP-based wave64 sum; result valid in lane 63 only.
template <int CTRL>
__device__ __forceinline__ float dpp_add(float v) {
  int m = __builtin_amdgcn_update_dpp(0, __float_as_int(v), CTRL, 0xf, 0xf, true);
  return v + __int_as_float(m);
}
__device__ __forceinline__ float wave_sum63(float v) {
  v = dpp_add<0x111>(v);  // row_shr:1
  v = dpp_add<0x112>(v);  // row_shr:2
  v = dpp_add<0x114>(v);  // row_shr:4
  v = dpp_add<0x118>(v);  // row_shr:8  -> lane15 of each row has row sum
  v = dpp_add<0x142>(v);  // row_bcast:15
  v = dpp_add<0x143>(v);  // row_bcast:31 -> lane63 has wave sum
  return v;
}

// Problem constants
// B=64 T=512 E=300 V=50000 H=2048 WP=2 OUT=5
// padded: EP=320, TP=516, KP=1600, M=B*T=32768

// ---------- kernel 1: W1 -> W1bT bf16 [2048][1600] (transposed, K-padded) ----------
__global__ __launch_bounds__(256) void prepw1_kernel(
    const float* __restrict__ W1, unsigned short* __restrict__ W1bT) {
  __shared__ float tile[64][65];
  int kb = blockIdx.x % 25;   // K tile (padded K = 1600 = 25*64)
  int hb = blockIdx.x / 25;   // H tile (2048 = 32*64)
  int win = kb / 5;
  int e0 = (kb % 5) << 6;
  int hh = threadIdx.x & 63;
  int kq = threadIdx.x >> 6;
#pragma unroll
  for (int kk = kq; kk < 64; kk += 4) {
    int e = e0 + kk;
    float v = 0.f;
    if (e < 300) v = W1[(size_t)(win * 300 + e) * 2048 + hb * 64 + hh];
    tile[kk][hh] = v;
  }
  __syncthreads();
  int kk = threadIdx.x & 63;
  int hq = threadIdx.x >> 6;
#pragma unroll
  for (int h = hq; h < 64; h += 4) {
    W1bT[(size_t)(hb * 64 + h) * 1600 + kb * 64 + kk] = f2bf(tile[kk][h]);
  }
}

// ---------- kernel 2: gather embeddings -> P bf16 [64][516][320] ----------
__global__ __launch_bounds__(320) void gather_kernel(
    const int* __restrict__ idxs, const float* __restrict__ emb,
    unsigned short* __restrict__ P) {
  int g = blockIdx.x;   // b*516 + tp
  int b = g / 516;
  int tp = g - b * 516;
  int tok = 0;
  if (tp >= 2 && tp < 514) tok = idxs[b * 512 + tp - 2];
  int e = threadIdx.x;
  float v = (e < 300) ? emb[(size_t)tok * 300 + e] : 0.f;
  P[(size_t)g * 320 + e] = f2bf(v);
}

// ---------- kernel 3: GEMM  Z[b*512+t][h] = sum_k A * W1bT + b1[h]  (bf16, f32 acc) ----------
// T2 bank-conflict fix (both-sides swizzle, rule #21): LDS dest stays linear;
// the global SOURCE of 16B chunk (row,kb) is pre-swizzled to (row, kb^(row&7));
// the ds_read XORs the same involution back in.  Data bitwise identical.
__global__ __launch_bounds__(256) void gemm_kernel(
    const unsigned short* __restrict__ P,
    const unsigned short* __restrict__ W1bT,
    const float* __restrict__ b1,
    unsigned short* __restrict__ Z) {
  __shared__ unsigned short As[128 * 64];  // [row][k] 16KB (swizzled slots)
  __shared__ unsigned short Bs[128 * 64];  // [col][k] 16KB (swizzled slots)
  const int tid = threadIdx.x;
  const int lane = tid & 63;
  const int w = tid >> 6;
  const int wm = w >> 1, wn = w & 1;
  const int lr = lane & 15;
  const int lk = (lane >> 4) << 3;

  const int nt = blockIdx.x & 15;   // 2048/128
  const int mt = blockIdx.x >> 4;   // 32768/128
  const int b = mt >> 2;            // 4 tiles per batch
  const int t0 = (mt & 3) << 7;

  f32x4 acc[4][4];
#pragma unroll
  for (int i = 0; i < 4; i++)
#pragma unroll
    for (int j = 0; j < 4; j++) acc[i][j] = (f32x4){0.f, 0.f, 0.f, 0.f};

  for (int kt = 0; kt < 25; ++kt) {
    const int win = kt / 5;
    const int e0 = (kt % 5) << 6;
#pragma unroll
    for (int j = 0; j < 4; ++j) {
      int chunk = tid + j * 256;
      int row = chunk >> 3, kb = chunk & 7;
      int kbs = kb ^ (row & 7);  // pre-swizzled source slot
      const unsigned short* src =
          P + (size_t)(b * 516 + t0 + row + win) * 320 + e0 + (kbs << 3);
      __builtin_amdgcn_global_load_lds(
          (const __attribute__((address_space(1))) unsigned int*)src,
          (__attribute__((address_space(3))) unsigned int*)&As[chunk << 3],
          16, 0, 0);
    }
#pragma unroll
    for (int j = 0; j < 4; ++j) {
      int chunk = tid + j * 256;
      int col = chunk >> 3, kb = chunk & 7;
      int kbs = kb ^ (col & 7);  // pre-swizzled source slot
      const unsigned short* src =
          W1bT + (size_t)(nt * 128 + col) * 1600 + (kt << 6) + (kbs << 3);
      __builtin_amdgcn_global_load_lds(
          (const __attribute__((address_space(1))) unsigned int*)src,
          (__attribute__((address_space(3))) unsigned int*)&Bs[chunk << 3],
          16, 0, 0);
    }
    __syncthreads();
#pragma unroll
    for (int ks = 0; ks < 64; ks += 32) {
      const int slot = (ks + lk) >> 3;  // 16B slot index 0..7
      bf16x8 af[4], bv[4];
#pragma unroll
      for (int am = 0; am < 4; ++am) {
        int row = (wm << 6) + (am << 4) + lr;
        af[am] = *(const bf16x8*)&As[(row << 6) + ((slot ^ (row & 7)) << 3)];
      }
#pragma unroll
      for (int bn = 0; bn < 4; ++bn) {
        int col = (wn << 6) + (bn << 4) + lr;
        bv[bn] = *(const bf16x8*)&Bs[(col << 6) + ((slot ^ (col & 7)) << 3)];
      }
#pragma unroll
      for (int am = 0; am < 4; ++am)
#pragma unroll
        for (int bn = 0; bn < 4; ++bn)
          acc[am][bn] = __builtin_amdgcn_mfma_f32_16x16x32_bf16(
              af[am], bv[bn], acc[am][bn], 0, 0, 0);
    }
    __syncthreads();
  }

  const int rbase = mt * 128 + (wm << 6) + ((lane >> 4) << 2);
  const int cbase = nt * 128 + (wn << 6) + lr;
  float b1v[4];
#pragma unroll
  for (int bn = 0; bn < 4; ++bn) b1v[bn] = b1[cbase + (bn << 4)];
#pragma unroll
  for (int am = 0; am < 4; ++am)
#pragma unroll
    for (int bn = 0; bn < 4; ++bn)
#pragma unroll
      for (int j = 0; j < 4; ++j) {
        int r = rbase + (am << 4) + j;
        int c = cbase + (bn << 4);
        Z[(size_t)r * 2048 + c] = f2bf(acc[am][bn][j] + b1v[bn]);
      }
}

// ---------- kernel 4: sequential scan, one block (4 waves) per batch ----------
// State recurrence split: prev = [p(t-2) | p(t-1)].  Only the p(t-1) half
// depends on the just-computed softmax; the p(t-2) half is folded into
// xcur = z_t + sum_i p(t-2)[i]*W1p[i] one iteration EARLY (xnext), whose
// 28 insts are partial-independent and fill the post-barrier LDS-read
// latency shadow.  Raw s_barrier + lgkmcnt(0) only (Z prefetch stays in
// flight).  Logits go to an LDS side-buffer (wave0 lane0, 20B/step); one
// cooperative coalesced store after the loop.
__global__ __launch_bounds__(256, 1) void scan_kernel(
    const unsigned short* __restrict__ Z, const float* __restrict__ W1,
    const float* __restrict__ W2, const float* __restrict__ b2,
    const float* __restrict__ istate, float* __restrict__ out) {
  const int b = blockIdx.x;
  const int tid = threadIdx.x;
  const int lane = tid & 63;
  const int wv = tid >> 6;  // 0..3
  const unsigned short* Zb = Z + (size_t)b * 512 * 2048;
  float* outb = out + (size_t)b * 512 * 5;

  // per-thread weight registers: four h-pairs, packed.  w1p[q][i], i=0..9
  f32x2 w1p[4][10];
#pragma unroll
  for (int i = 0; i < 10; ++i) {
    const float* row = &W1[(size_t)(1500 + i) * 2048 + tid * 8];
#pragma unroll
    for (int q = 0; q < 4; ++q) w1p[q][i] = *(const f32x2*)&row[q * 2];
  }
  f32x2 w2p[4][5];
#pragma unroll
  for (int k = 0; k < 5; ++k)
#pragma unroll
    for (int q = 0; q < 4; ++q)
      w2p[q][k] = (f32x2){W2[(tid * 8 + 2 * q) * 5 + k],
                          W2[(tid * 8 + 2 * q + 1) * 5 + k]};
  const float b20 = b2[0], b21 = b2[1], b22 = b2[2], b23 = b2[3],
              b24 = b2[4];
  const float L2E = 1.4426950408889634f;

  __shared__ float part[2][4][8];     // [parity][wave][k(padded to 8)]
  __shared__ float out_lds[512][8];   // logits side-buffer (16KB, 32B rows)

  // ---- prologue ----
  // pf = fresh half = p(t-1); for t=0 that's istate[5..9]
  float pf0 = istate[5], pf1 = istate[6], pf2 = istate[7], pf3 = istate[8],
        pf4 = istate[9];
  // xcur = z_0 + sum_{i<5} istate[i]*w1p[i]
  u16x8 zc0 = *(const u16x8*)&Zb[tid * 8];
  u16x8 zn = *(const u16x8*)&Zb[(size_t)2048 + tid * 8];
  u16x8 zf = *(const u16x8*)&Zb[(size_t)2 * 2048 + tid * 8];
  f32x2 xc[4];
  xc[0] = (f32x2){bf2f(zc0[0]), bf2f(zc0[1])};
  xc[1] = (f32x2){bf2f(zc0[2]), bf2f(zc0[3])};
  xc[2] = (f32x2){bf2f(zc0[4]), bf2f(zc0[5])};
  xc[3] = (f32x2){bf2f(zc0[6]), bf2f(zc0[7])};
#pragma unroll
  for (int i = 0; i < 5; ++i) {
    const float oi = istate[i];
#pragma unroll
    for (int q = 0; q < 4; ++q) xc[q] = oi * w1p[q][i] + xc[q];
  }

  for (int t = 0; t < 512; ++t) {
    // ---- fresh-half FMAs (only 5, dependent on last softmax) ----
    f32x2 x0 = xc[0], x1 = xc[1], x2 = xc[2], x3 = xc[3];
    x0 = pf0 * w1p[0][5] + x0; x1 = pf0 * w1p[1][5] + x1;
    x2 = pf0 * w1p[2][5] + x2; x3 = pf0 * w1p[3][5] + x3;
    x0 = pf1 * w1p[0][6] + x0; x1 = pf1 * w1p[1][6] + x1;
    x2 = pf1 * w1p[2][6] + x2; x3 = pf1 * w1p[3][6] + x3;
    x0 = pf2 * w1p[0][7] + x0; x1 = pf2 * w1p[1][7] + x1;
    x2 = pf2 * w1p[2][7] + x2; x3 = pf2 * w1p[3][7] + x3;
    x0 = pf3 * w1p[0][8] + x0; x1 = pf3 * w1p[1][8] + x1;
    x2 = pf3 * w1p[2][8] + x2; x3 = pf3 * w1p[3][8] + x3;
    x0 = pf4 * w1p[0][9] + x0; x1 = pf4 * w1p[1][9] + x1;
    x2 = pf4 * w1p[2][9] + x2; x3 = pf4 * w1p[3][9] + x3;
    const f32x2 zero2 = (f32x2){0.f, 0.f};
    x0 = __builtin_elementwise_max(x0, zero2);
    x1 = __builtin_elementwise_max(x1, zero2);
    x2 = __builtin_elementwise_max(x2, zero2);
    x3 = __builtin_elementwise_max(x3, zero2);
    f32x2 a0 = x0 * w2p[0][0] + x1 * w2p[1][0];
    f32x2 a1 = x0 * w2p[0][1] + x1 * w2p[1][1];
    f32x2 a2 = x0 * w2p[0][2] + x1 * w2p[1][2];
    f32x2 a3 = x0 * w2p[0][3] + x1 * w2p[1][3];
    f32x2 a4 = x0 * w2p[0][4] + x1 * w2p[1][4];
    a0 = x2 * w2p[2][0] + a0;  a0 = x3 * w2p[3][0] + a0;
    a1 = x2 * w2p[2][1] + a1;  a1 = x3 * w2p[3][1] + a1;
    a2 = x2 * w2p[2][2] + a2;  a2 = x3 * w2p[3][2] + a2;
    a3 = x2 * w2p[2][3] + a3;  a3 = x3 * w2p[3][3] + a3;
    a4 = x2 * w2p[2][4] + a4;  a4 = x3 * w2p[3][4] + a4;
    float y0 = a0.x + a0.y, y1 = a1.x + a1.y, y2 = a2.x + a2.y,
          y3 = a3.x + a3.y, y4 = a4.x + a4.y;

    // prefetch row t+3 (consumed at t+2; stays in flight across barriers)
    int tn = (t + 3 < 512) ? (t + 3) : 511;
    u16x8 zfn = *(const u16x8*)&Zb[(size_t)tn * 2048 + tid * 8];

    // ---- intra-wave DPP reduce, sums land in lane 63 ----
    y0 = wave_sum63(y0);
    y1 = wave_sum63(y1);
    y2 = wave_sum63(y2);
    y3 = wave_sum63(y3);
    y4 = wave_sum63(y4);
    const int pp = t & 1;
    if (lane == 63) {
      *(float4*)&part[pp][wv][0] = (float4){y0, y1, y2, y3};
      part[pp][wv][4] = y4;
    }
    // raw barrier: drain LDS only (Z prefetch stays in flight)
    asm volatile("s_waitcnt lgkmcnt(0)" ::: "memory");
    __builtin_amdgcn_sched_barrier(0);
    __builtin_amdgcn_s_barrier();
    __builtin_amdgcn_sched_barrier(0);

    // ---- stage B (redundant on all threads) + xnext in the LDS shadow ----
    f32x4 q0 = *(const f32x4*)&part[pp][0][0];
    f32x4 q1 = *(const f32x4*)&part[pp][1][0];
    f32x4 q2 = *(const f32x4*)&part[pp][2][0];
    f32x4 q3 = *(const f32x4*)&part[pp][3][0];
    f32x4 sv = (q0 + q1) + (q2 + q3);
    float s4 = (part[pp][0][4] + part[pp][1][4]) +
               (part[pp][2][4] + part[pp][3][4]);
    float s0 = sv.x + b20, s1 = sv.y + b21, s2 = sv.z + b22,
          s3 = sv.w + b23;
    s4 += b24;

    // xnext for t+1: old half = pf (= p(t-1)), z row t+1 from zn.
    // Independent of part[] -> scheduler hides it under the LDS reads.
    f32x2 xn0 = (f32x2){bf2f(zn[0]), bf2f(zn[1])};
    f32x2 xn1 = (f32x2){bf2f(zn[2]), bf2f(zn[3])};
    f32x2 xn2 = (f32x2){bf2f(zn[4]), bf2f(zn[5])};
    f32x2 xn3 = (f32x2){bf2f(zn[6]), bf2f(zn[7])};
    xn0 = pf0 * w1p[0][0] + xn0; xn1 = pf0 * w1p[1][0] + xn1;
    xn2 = pf0 * w1p[2][0] + xn2; xn3 = pf0 * w1p[3][0] + xn3;
    xn0 = pf1 * w1p[0][1] + xn0; xn1 = pf1 * w1p[1][1] + xn1;
    xn2 = pf1 * w1p[2][1] + xn2; xn3 = pf1 * w1p[3][1] + xn3;
    xn0 = pf2 * w1p[0][2] + xn0; xn1 = pf2 * w1p[1][2] + xn1;
    xn2 = pf2 * w1p[2][2] + xn2; xn3 = pf2 * w1p[3][2] + xn3;
    xn0 = pf3 * w1p[0][3] + xn0; xn1 = pf3 * w1p[1][3] + xn1;
    xn2 = pf3 * w1p[2][3] + xn2; xn3 = pf3 * w1p[3][3] + xn3;
    xn0 = pf4 * w1p[0][4] + xn0; xn1 = pf4 * w1p[1][4] + xn1;
    xn2 = pf4 * w1p[2][4] + xn2; xn3 = pf4 * w1p[3][4] + xn3;

    // logits -> LDS side-buffer (one thread; no global stores in loop)
    if (tid == 0) {
      *(float4*)&out_lds[t][0] = (float4){s0, s1, s2, s3};
      out_lds[t][4] = s4;
    }

    // ---- softmax (max-sub needed: |logits| reach ~500) ----
    float m = fmaxf(fmaxf(fmaxf(s0, s1), fmaxf(s2, s3)), s4);
    float mL = m * L2E;
    float e0 = __builtin_amdgcn_exp2f(fmaf(s0, L2E, -mL));
    float e1 = __builtin_amdgcn_exp2f(fmaf(s1, L2E, -mL));
    float e2 = __builtin_amdgcn_exp2f(fmaf(s2, L2E, -mL));
    float e3 = __builtin_amdgcn_exp2f(fmaf(s3, L2E, -mL));
    float e4 = __builtin_amdgcn_exp2f(fmaf(s4, L2E, -mL));
    float d = ((e0 + e1) + (e2 + e3)) + e4;
    float rd = __builtin_amdgcn_rcpf(d);
    pf0 = e0 * rd; pf1 = e1 * rd; pf2 = e2 * rd; pf3 = e3 * rd;
    pf4 = e4 * rd;

    xc[0] = xn0; xc[1] = xn1; xc[2] = xn2; xc[3] = xn3;
    zn = zf; zf = zfn;
  }

  __syncthreads();
  // cooperative coalesced store: thread tid owns steps 2*tid, 2*tid+1
  {
    const int r0 = tid * 2, r1 = tid * 2 + 1;
    float o[10];
#pragma unroll
    for (int i = 0; i < 5; ++i) o[i] = out_lds[r0][i];
#pragma unroll
    for (int i = 0; i < 5; ++i) o[5 + i] = out_lds[r1][i];
    float* dst = outb + tid * 10;
#pragma unroll
    for (int i = 0; i < 10; ++i) dst[i] = o[i];
  }
}

// ---------- launcher ----------
extern "C" void kernel_launch(void* const* d_in, const int* in_sizes, int n_in,
                              void* d_out, int out_size, void* d_ws,
                              size_t ws_size, hipStream_t stream) {
  const int* idxs = (const int*)d_in[0];
  const float* emb = (const float*)d_in[1];
  const float* W1 = (const float*)d_in[2];
  const float* b1 = (const float*)d_in[3];
  const float* W2 = (const float*)d_in[4];
  const float* b2 = (const float*)d_in[5];
  const float* istate = (const float*)d_in[6];
  float* out = (float*)d_out;

  char* ws = (char*)d_ws;
  unsigned short* P = (unsigned short*)ws;                          // 21,135,360 B
  unsigned short* W1bT = (unsigned short*)(ws + 21135360);          // 6,553,600 B
  unsigned short* Z = (unsigned short*)(ws + 21135360 + 6553600);   // 134,217,728 B

  hipLaunchKernelGGL(prepw1_kernel, dim3(25 * 32), dim3(256), 0, stream, W1, W1bT);
  hipLaunchKernelGGL(gather_kernel, dim3(64 * 516), dim3(320), 0, stream, idxs, emb, P);
  hipLaunchKernelGGL(gemm_kernel, dim3(256 * 16), dim3(256), 0, stream, P, W1bT, b1, Z);
  hipLaunchKernelGGL(scan_kernel, dim3(64), dim3(256), 0, stream, Z, W1, W2, b2,
                     istate, out);
}